// Round 11
// baseline (89.285 us; speedup 1.0000x reference)
//
#include <hip/hip_runtime.h>
#include <stdint.h>

// Problem constants
#define B 16
#define T 256
#define NP 2304           // H*W = 48*48
#define START 127         // start_idx = min(max(128-1,0), T-1)
#define NCOL 576          // NP/4 float4 columns per batch
#define TS 8              // time splits: 17 + 7*16 = 129 steps
#define NBINS 21          // bins of width 0.05 over (0,1); clamp catches edge rounding
#define BINW 20.0f
#define BPB 144           // output blocks per batch (2304 total)
#define OITER 36          // float4 stores per thread: NP*NCOL / (BPB*256)

typedef unsigned int u32;
typedef float f4v __attribute__((ext_vector_type(4)));  // native vector for nt-store

__device__ inline float4 f4add(float4 x, float4 y) {
    return make_float4(x.x + y.x, x.y + y.y, x.z + y.z, x.w + y.w);
}

// Kernel A: partial time sums. Grid 288x256; task = (batch, t-eighth, float4 col).
__global__ __launch_bounds__(256) void kA_partial(const float* __restrict__ in,
                                                  float4* __restrict__ part) {
    int gid = blockIdx.x * 256 + threadIdx.x;        // 0..73727
    int b   = gid / (TS * NCOL);
    int rem = gid - b * (TS * NCOL);
    int q   = rem / NCOL;
    int col = rem - q * NCOL;
    int t0  = (q == 0) ? START : (START + 17 + 16 * (q - 1));  // 127,144,...,240
    int nt  = (q == 0) ? 17 : 16;
    const float4* p = (const float4*)(in + ((size_t)b * T + t0) * NP) + col;
    float4 z = make_float4(0.f, 0.f, 0.f, 0.f);
    float4 a0 = z, a1 = z, a2 = z, a3 = z, a4 = z, a5 = z, a6 = z, a7 = z;
    int t = 0;
    for (; t + 8 <= nt; t += 8) {
        a0 = f4add(a0, p[(size_t)(t + 0) * NCOL]);
        a1 = f4add(a1, p[(size_t)(t + 1) * NCOL]);
        a2 = f4add(a2, p[(size_t)(t + 2) * NCOL]);
        a3 = f4add(a3, p[(size_t)(t + 3) * NCOL]);
        a4 = f4add(a4, p[(size_t)(t + 4) * NCOL]);
        a5 = f4add(a5, p[(size_t)(t + 5) * NCOL]);
        a6 = f4add(a6, p[(size_t)(t + 6) * NCOL]);
        a7 = f4add(a7, p[(size_t)(t + 7) * NCOL]);
    }
    for (; t < nt; ++t) a0 = f4add(a0, p[(size_t)t * NCOL]);
    float4 s = f4add(f4add(f4add(a0, a1), f4add(a2, a3)),
                     f4add(f4add(a4, a5), f4add(a6, a7)));
    part[(b * TS + q) * NCOL + col] = s;
}

// Kernel OUT: per-block redundant histogram clustering (own batch) + direct
// computed-write of the one-hot masks. One nt store per output element — no
// separate fill, no scatter, no cross-block ordering.
// Clustering: bin width 0.05 < EPS => within-bin pairs always connected; the
// only candidate break is (max of lower occupied bin, min of next occupied
// bin), tested with the same f32 compare (gap > 0.1f) as the reference.
__global__ __launch_bounds__(256) void kOut(const float* __restrict__ partF,
                                            f4v* __restrict__ out4) {
    int blk = blockIdx.x;                 // 0..2303
    int bb  = blk / BPB;                  // batch
    int sub = blk - bb * BPB;             // 0..143
    int tid = threadIdx.x;

    __shared__ u32 binMinV[NBINS], binMaxV[NBINS], binMinI[NBINS];
    __shared__ int binRow[NBINS];
    __shared__ int compOfBin[NBINS];
    __shared__ u32 compMinI[NBINS];
    __shared__ unsigned char binOf[NP];
    __shared__ __align__(8) unsigned short rvArr[NP];

    if (tid < NBINS) {
        binMinV[tid] = 0xFFFFFFFFu;
        binMaxV[tid] = 0u;
        binMinI[tid] = 0xFFFFFFFFu;
    }
    __syncthreads();

    const float* pb = partF + (size_t)bb * TS * NP;

    // per-thread run-merged atomic updates (few hot bins -> runs are common)
    int curBin = -1;
    u32 cMin = 0, cMax = 0, cIdx = 0;
    for (int p = tid; p < NP; p += 256) {
        float s0 = pb[0 * NP + p], s1 = pb[1 * NP + p];
        float s2 = pb[2 * NP + p], s3 = pb[3 * NP + p];
        float s4 = pb[4 * NP + p], s5 = pb[5 * NP + p];
        float s6 = pb[6 * NP + p], s7 = pb[7 * NP + p];
        float s = ((s0 + s1) + (s2 + s3)) + ((s4 + s5) + (s6 + s7));
        float avg = s / 129.0f;
        int bin = (int)(avg * BINW);
        bin = bin < 0 ? 0 : (bin > NBINS - 1 ? NBINS - 1 : bin);
        binOf[p] = (unsigned char)bin;
        u32 vb = __float_as_uint(avg);              // positive floats: bits order-preserving
        if (bin == curBin) {
            cMin = min(cMin, vb);
            cMax = max(cMax, vb);
            cIdx = min(cIdx, (u32)p);
        } else {
            if (curBin >= 0) {
                atomicMin(&binMinV[curBin], cMin);
                atomicMax(&binMaxV[curBin], cMax);
                atomicMin(&binMinI[curBin], cIdx);
            }
            curBin = bin; cMin = vb; cMax = vb; cIdx = (u32)p;
        }
    }
    if (curBin >= 0) {
        atomicMin(&binMinV[curBin], cMin);
        atomicMax(&binMaxV[curBin], cMax);
        atomicMin(&binMinI[curBin], cIdx);
    }
    __syncthreads();

    if (tid == 0) {
        // merge consecutive occupied bins into components
        int K = 0, prev = -1;
        for (int bn = 0; bn < NBINS; ++bn) {
            if (binMinI[bn] == 0xFFFFFFFFu) continue;
            bool newc;
            if (prev < 0) {
                newc = true;
            } else {
                float gap = __uint_as_float(binMinV[bn]) - __uint_as_float(binMaxV[prev]);
                newc = (gap > 0.1f);                // EPS = 1-0.9 rounds to 0.1f
            }
            if (newc) {
                compMinI[K] = binMinI[bn];
                ++K;
            } else {
                compMinI[K - 1] = min(compMinI[K - 1], binMinI[bn]);
            }
            compOfBin[bn] = K - 1;
            prev = bn;
        }
        // rank components by smallest pixel index (reference discovery order)
        for (int bn = 0; bn < NBINS; ++bn) {
            if (binMinI[bn] == 0xFFFFFFFFu) { binRow[bn] = 0; continue; }
            u32 mi = compMinI[compOfBin[bn]];
            int r = 0;
            for (int c = 0; c < K; ++c) r += (compMinI[c] < mi) ? 1 : 0;
            binRow[bn] = r;
        }
    }
    __syncthreads();

    // rv[p] = output row of pixel p (u16; rows < 2304)
    for (int p = tid; p < NP; p += 256) {
        rvArr[p] = (unsigned short)binRow[binOf[p]];
    }
    __syncthreads();

    // streaming computed-write: 144 blocks sweep this batch's contiguous
    // region grid-stride (channel-uniform window, same shape as proven fill)
    const ushort4* rvp = (const ushort4*)rvArr;
    f4v* ob = out4 + (size_t)bb * (NP * NCOL);
#pragma unroll
    for (int k = 0; k < OITER; ++k) {
        u32 pos = (u32)sub * 256 + tid + (u32)k * (BPB * 256);  // 0..1327103
        u32 row = pos / NCOL;
        u32 col4 = pos - row * NCOL;
        ushort4 rv4 = rvp[col4];
        f4v v;
        v.x = (rv4.x == row) ? 1.f : 0.f;
        v.y = (rv4.y == row) ? 1.f : 0.f;
        v.z = (rv4.z == row) ? 1.f : 0.f;
        v.w = (rv4.w == row) ? 1.f : 0.f;
        __builtin_nontemporal_store(v, &ob[pos]);
    }
}

extern "C" void kernel_launch(void* const* d_in, const int* in_sizes, int n_in,
                              void* d_out, int out_size, void* d_ws, size_t ws_size,
                              hipStream_t stream) {
    const float* in = (const float*)d_in[0];
    float* out = (float*)d_out;
    char* ws = (char*)d_ws;
    // ws layout: part [B*TS*NCOL float4 = 1179648 B]
    float4* part = (float4*)ws;

    kA_partial<<<(B * TS * NCOL) / 256, 256, 0, stream>>>(in, part);
    kOut<<<B * BPB, 256, 0, stream>>>((const float*)part, (f4v*)out);
}

// Round 12
// 75.399 us; speedup vs baseline: 1.1842x; 1.1842x over previous
//
#include <hip/hip_runtime.h>
#include <stdint.h>

// Problem constants
#define B 16
#define T 256
#define NP 2304           // H*W = 48*48
#define START 127         // start_idx = min(max(128-1,0), T-1)
#define NCOL 576          // NP/4 float4 columns per batch
#define TS 8              // time splits: 17 + 7*16 = 129 steps
#define NBINS 21          // bins of width 0.05 over (0,1); clamp catches edge rounding
#define BINW 20.0f
#define FILL_BLOCKS 2304
#define FILL_ITERS 36     // B*NP*NP/4 / (FILL_BLOCKS*256) == 36 exactly

typedef unsigned int u32;
typedef float f4v __attribute__((ext_vector_type(4)));  // native vector for nt-store

__device__ inline float4 f4add(float4 x, float4 y) {
    return make_float4(x.x + y.x, x.y + y.y, x.z + y.z, x.w + y.w);
}

// Kernel F: zero-fill 340MB with nontemporal grid-stride stores.
// Pure store stream — every fused variant (lane/wave/block/coop/computed-write)
// measured slower; dedicated fill dispatch is the platform optimum.
__global__ __launch_bounds__(256) void kFill(f4v* __restrict__ out4) {
    size_t idx = (size_t)blockIdx.x * 256 + threadIdx.x;
    const size_t stride = (size_t)FILL_BLOCKS * 256;
    f4v z = (f4v)(0.0f);
#pragma unroll
    for (int k = 0; k < FILL_ITERS; ++k) {
        __builtin_nontemporal_store(z, &out4[idx + (size_t)k * stride]);
    }
}

// Kernel A: partial time sums. Grid 288x256; task = (batch, t-eighth, float4 col).
__global__ __launch_bounds__(256) void kA_partial(const float* __restrict__ in,
                                                  float4* __restrict__ part) {
    int gid = blockIdx.x * 256 + threadIdx.x;        // 0..73727
    int b   = gid / (TS * NCOL);
    int rem = gid - b * (TS * NCOL);
    int q   = rem / NCOL;
    int col = rem - q * NCOL;
    int t0  = (q == 0) ? START : (START + 17 + 16 * (q - 1));  // 127,144,...,240
    int nt  = (q == 0) ? 17 : 16;
    const float4* p = (const float4*)(in + ((size_t)b * T + t0) * NP) + col;
    float4 z = make_float4(0.f, 0.f, 0.f, 0.f);
    float4 a0 = z, a1 = z, a2 = z, a3 = z, a4 = z, a5 = z, a6 = z, a7 = z;
    int t = 0;
    for (; t + 8 <= nt; t += 8) {
        a0 = f4add(a0, p[(size_t)(t + 0) * NCOL]);
        a1 = f4add(a1, p[(size_t)(t + 1) * NCOL]);
        a2 = f4add(a2, p[(size_t)(t + 2) * NCOL]);
        a3 = f4add(a3, p[(size_t)(t + 3) * NCOL]);
        a4 = f4add(a4, p[(size_t)(t + 4) * NCOL]);
        a5 = f4add(a5, p[(size_t)(t + 5) * NCOL]);
        a6 = f4add(a6, p[(size_t)(t + 6) * NCOL]);
        a7 = f4add(a7, p[(size_t)(t + 7) * NCOL]);
    }
    for (; t < nt; ++t) a0 = f4add(a0, p[(size_t)t * NCOL]);
    float4 s = f4add(f4add(f4add(a0, a1), f4add(a2, a3)),
                     f4add(f4add(a4, a5), f4add(a6, a7)));
    part[(b * TS + q) * NCOL + col] = s;
}

// Kernel B2: per-batch histogram clustering -> scatter ones directly.
// Bin width 0.05 < EPS: within-bin pairs always connected; the only candidate
// break is between (max of lower occupied bin, min of next occupied bin),
// tested with the same f32 compare (gap > 0.1f) as the reference's sorted scan.
__global__ __launch_bounds__(256) void kB2(const float* __restrict__ partF,
                                           float* __restrict__ out) {
    int b = blockIdx.x;
    int tid = threadIdx.x;
    __shared__ u32 binMinV[NBINS], binMaxV[NBINS], binMinI[NBINS];
    __shared__ int binRow[NBINS];
    __shared__ int compOfBin[NBINS];
    __shared__ u32 compMinI[NBINS];
    __shared__ unsigned char binOf[NP];

    if (tid < NBINS) {
        binMinV[tid] = 0xFFFFFFFFu;
        binMaxV[tid] = 0u;
        binMinI[tid] = 0xFFFFFFFFu;
    }
    __syncthreads();

    const float* pb = partF + (size_t)b * TS * NP;

    // per-thread run-merged atomic updates (few hot bins -> runs are common)
    int curBin = -1;
    u32 cMin = 0, cMax = 0, cIdx = 0;
    for (int p = tid; p < NP; p += 256) {
        float s0 = pb[0 * NP + p], s1 = pb[1 * NP + p];
        float s2 = pb[2 * NP + p], s3 = pb[3 * NP + p];
        float s4 = pb[4 * NP + p], s5 = pb[5 * NP + p];
        float s6 = pb[6 * NP + p], s7 = pb[7 * NP + p];
        float s = ((s0 + s1) + (s2 + s3)) + ((s4 + s5) + (s6 + s7));
        float avg = s / 129.0f;
        int bin = (int)(avg * BINW);
        bin = bin < 0 ? 0 : (bin > NBINS - 1 ? NBINS - 1 : bin);
        binOf[p] = (unsigned char)bin;
        u32 vb = __float_as_uint(avg);              // positive floats: bits order-preserving
        if (bin == curBin) {
            cMin = min(cMin, vb);
            cMax = max(cMax, vb);
            cIdx = min(cIdx, (u32)p);
        } else {
            if (curBin >= 0) {
                atomicMin(&binMinV[curBin], cMin);
                atomicMax(&binMaxV[curBin], cMax);
                atomicMin(&binMinI[curBin], cIdx);
            }
            curBin = bin; cMin = vb; cMax = vb; cIdx = (u32)p;
        }
    }
    if (curBin >= 0) {
        atomicMin(&binMinV[curBin], cMin);
        atomicMax(&binMaxV[curBin], cMax);
        atomicMin(&binMinI[curBin], cIdx);
    }
    __syncthreads();

    if (tid == 0) {
        // merge consecutive occupied bins into components
        int K = 0, prev = -1;
        for (int bn = 0; bn < NBINS; ++bn) {
            if (binMinI[bn] == 0xFFFFFFFFu) continue;
            bool newc;
            if (prev < 0) {
                newc = true;
            } else {
                float gap = __uint_as_float(binMinV[bn]) - __uint_as_float(binMaxV[prev]);
                newc = (gap > 0.1f);                // EPS = 1-0.9 rounds to 0.1f
            }
            if (newc) {
                compMinI[K] = binMinI[bn];
                ++K;
            } else {
                compMinI[K - 1] = min(compMinI[K - 1], binMinI[bn]);
            }
            compOfBin[bn] = K - 1;
            prev = bn;
        }
        // rank components by smallest pixel index (reference discovery order)
        for (int bn = 0; bn < NBINS; ++bn) {
            if (binMinI[bn] == 0xFFFFFFFFu) { binRow[bn] = 0; continue; }
            u32 mi = compMinI[compOfBin[bn]];
            int r = 0;
            for (int c = 0; c < K; ++c) r += (compMinI[c] < mi) ? 1 : 0;
            binRow[bn] = r;
        }
    }
    __syncthreads();

    // scatter the exactly NP ones for this batch (consecutive p share a row
    // almost always -> coalesced stores)
    float* ob = out + (size_t)b * NP * NP;
    for (int p = tid; p < NP; p += 256) {
        int r = binRow[binOf[p]];
        ob[(size_t)r * NP + p] = 1.0f;
    }
}

extern "C" void kernel_launch(void* const* d_in, const int* in_sizes, int n_in,
                              void* d_out, int out_size, void* d_ws, size_t ws_size,
                              hipStream_t stream) {
    const float* in = (const float*)d_in[0];
    float* out = (float*)d_out;
    char* ws = (char*)d_ws;
    // ws layout: part [B*TS*NCOL float4 = 1179648 B]
    float4* part = (float4*)ws;

    kA_partial<<<(B * TS * NCOL) / 256, 256, 0, stream>>>(in, part);
    kFill<<<FILL_BLOCKS, 256, 0, stream>>>((f4v*)out);
    kB2<<<B, 256, 0, stream>>>((const float*)part, out);
}